// Round 10
// baseline (30.345 us; speedup 1.0000x reference)
//
#include <hip/hip_runtime.h>
#include <math.h>

#define BB 2048   // batch B
#define NN 512    // classes N
#define DD 256    // dim D

typedef __attribute__((ext_vector_type(8))) short s16x8;   // 8 bf16
typedef __attribute__((ext_vector_type(4))) float f32x4;

#define MFMA_BF16 __builtin_amdgcn_mfma_f32_16x16x32_bf16

__device__ __forceinline__ ushort f2bf(float f) {          // RNE f32->bf16
    union { float f; unsigned u; } c; c.f = f;
    return (ushort)((c.u + 0x7fffu + ((c.u >> 16) & 1u)) >> 16);
}
__device__ __forceinline__ float bf2f(ushort h) {
    union { unsigned u; float f; } c; c.u = ((unsigned)h) << 16;
    return c.f;
}

// scale 4 floats, split each into bf16 hi + bf16 lo (RNE both), pack pairs
__device__ __forceinline__ void split4(f32x4 v, float s, uint2* hi, uint2* lo) {
    float a = v.x * s, b = v.y * s, c = v.z * s, d = v.w * s;
    ushort ha = f2bf(a), hb = f2bf(b), hc = f2bf(c), hd = f2bf(d);
    ushort la = f2bf(a - bf2f(ha)), lb = f2bf(b - bf2f(hb));
    ushort lc = f2bf(c - bf2f(hc)), ld = f2bf(d - bf2f(hd));
    hi->x = (unsigned)ha | ((unsigned)hb << 16);
    hi->y = (unsigned)hc | ((unsigned)hd << 16);
    lo->x = (unsigned)la | ((unsigned)lb << 16);
    lo->y = (unsigned)lc | ((unsigned)ld << 16);
}

// ---------------- K1: X transform ONLY, one wave per row ----------------
// High occupancy (no LDS, 256-thr blocks). Writes bf16 hi/lo PRE-SWIZZLED
// (el ^= (row&7)<<3 within each 64-elem chunk) + y2 scalar.
__global__ __launch_bounds__(256) void hmlr_xform(
    const float* __restrict__ x,
    ushort* __restrict__ Xh, ushort* __restrict__ Xl, float* __restrict__ y2)
{
    const int lane = threadIdx.x & 63;
    const int r    = blockIdx.x * 4 + (threadIdx.x >> 6);   // 0..BB-1
    const int e0   = lane * 4;

    f32x4 v = *(const f32x4*)&x[(size_t)r * DD + e0];
    float ss = v.x * v.x + v.y * v.y + v.z * v.z + v.w * v.w;
    #pragma unroll
    for (int m = 32; m; m >>= 1) ss += __shfl_xor(ss, m, 64);
    float norm0 = sqrtf(ss);
    float fac = fminf(1.0f, 1.0f / (norm0 + 1e-5f));        // CLIP_R = 1
    float u = fmaxf(norm0 * fac, 1e-5f);
    float th = tanhf(u);                                     // sqrt_c = 1
    float en = fmaxf(th, 1e-5f);
    float wgt = (en > 0.999f) ? (0.999f / en) : 1.0f;        // project
    float s = fac * (th / u) * wgt;                          // x -> xb scale
    if (lane == 0) { float fn = th * wgt; y2[r] = fn * fn; }
    uint2 hi, lo;
    split4(v, s, &hi, &lo);
    int es = e0 ^ ((r & 7) << 3);                            // pre-swizzle
    *(uint2*)&Xh[(size_t)r * DD + es] = hi;
    *(uint2*)&Xl[(size_t)r * DD + es] = lo;
}

// ---------------- K2: stage X + transform own P/A + GEMM + epilogue ----
// Block (n0,b0): issue global_load_lds of its X tile (64 KiB) FIRST, then
// transform its 64 P/A rows into swizzled LDS (half-K trick: lanes>=32 keep
// K-half-1 in regs, overwrite after q=0..3). One barrier before GEMM.
// LDS (ushort offsets): sXh@0 [64][256], sXl@16384, sPh@32768 [64][128],
// sPl@40960, sAh@49152, sAl@57344, float scalars @65536.
__global__ __launch_bounds__(512, 1) void hmlr_main(
    const float* __restrict__ a_vals, const float* __restrict__ p_vals,
    const ushort* __restrict__ Xh, const ushort* __restrict__ Xl,
    const float* __restrict__ y2, float* __restrict__ out)
{
    extern __shared__ ushort T[];
    ushort* sXh = T;
    ushort* sXl = T + 16384;
    ushort* sPh = T + 32768;
    ushort* sPl = T + 40960;
    ushort* sAh = T + 49152;
    ushort* sAl = T + 57344;
    float* p2sl = (float*)(T + 65536);
    float* pasl = p2sl + 64;
    float* ansl = p2sl + 128;
    float* ksl  = p2sl + 192;

    const int t    = threadIdx.x;
    const int lane = t & 63;
    const int w    = t >> 6;               // wave 0..7
    const int n0   = blockIdx.x * 64;
    const int b0   = blockIdx.y * 64;

    // ---- phase A: issue X staging (pre-swizzled global -> linear LDS) ----
    {
        const ushort* gh = Xh + (size_t)(b0 + w * 8) * DD + (lane >> 5) * DD + (lane & 31) * 8;
        const ushort* gl = Xl + (size_t)(b0 + w * 8) * DD + (lane >> 5) * DD + (lane & 31) * 8;
        ushort* lh = sXh + (size_t)(w * 8) * DD;
        ushort* ll = sXl + (size_t)(w * 8) * DD;
        #pragma unroll
        for (int j = 0; j < 4; ++j) {      // 2 rows (1 KiB) per instruction
            __builtin_amdgcn_global_load_lds(
                (const __attribute__((address_space(1))) unsigned int*)(const void*)(gh + j * 2 * DD),
                (__attribute__((address_space(3))) unsigned int*)(void*)(lh + j * 2 * DD),
                16, 0, 0);
            __builtin_amdgcn_global_load_lds(
                (const __attribute__((address_space(1))) unsigned int*)(const void*)(gl + j * 2 * DD),
                (__attribute__((address_space(3))) unsigned int*)(void*)(ll + j * 2 * DD),
                16, 0, 0);
        }
    }

    // ---- phase B: transform this block's 64 P/A rows (overlaps X load) ----
    const int e0 = lane * 4;               // full-K elem base
    const int c0 = (lane & 31) * 4;        // half-K elem base
    uint2 ph1[8], pl1[8], ah1[8], al1[8];  // lanes>=32: K-half-1 hold
    #pragma unroll
    for (int i = 0; i < 8; ++i) {
        int rn = w * 8 + i;                // block-local n row
        f32x4 pv = *(const f32x4*)&p_vals[(size_t)(n0 + rn) * DD + e0];
        f32x4 av = *(const f32x4*)&a_vals[(size_t)(n0 + rn) * DD + e0];
        float sp = pv.x * pv.x + pv.y * pv.y + pv.z * pv.z + pv.w * pv.w;
        float sa = av.x * av.x + av.y * av.y + av.z * av.z + av.w * av.w;
        float sx = pv.x * av.x + pv.y * av.y + pv.z * av.z + pv.w * av.w;
        #pragma unroll
        for (int m = 32; m; m >>= 1) {
            sp += __shfl_xor(sp, m, 64);
            sa += __shfl_xor(sa, m, 64);
            sx += __shfl_xor(sx, m, 64);
        }
        float u = fmaxf(sqrtf(sp), 1e-5f);
        float th = tanhf(u);
        float spp = th / u;                                  // p -> p_poincare
        float p2 = th * th;
        float conf = 1.0f - p2;                              // conformal
        if (lane == 0) {
            p2sl[rn] = p2;
            pasl[rn] = spp * conf * sx;                      // P . A
            float an = sqrtf(sa) * conf;                     // ||a_poincare||
            ansl[rn] = an;
            ksl[rn] = (2.0f / conf) * an;                    // lam * a_norm
        }
        uint2 hp, lp, ha, la;
        split4(pv, spp, &hp, &lp);
        split4(av, conf, &ha, &la);
        int cs = c0 ^ ((rn & 7) << 3);
        if (lane < 32) {                                     // K-half 0 now
            *(uint2*)&sPh[rn * 128 + cs] = hp;
            *(uint2*)&sPl[rn * 128 + cs] = lp;
            *(uint2*)&sAh[rn * 128 + cs] = ha;
            *(uint2*)&sAl[rn * 128 + cs] = la;
        } else {                                             // hold K-half 1
            ph1[i] = hp; pl1[i] = lp; ah1[i] = ha; al1[i] = la;
        }
    }
    __syncthreads();                       // X resident + P/A half-0 written

    // ---- GEMM setup ----
    const int wr   = w >> 2;               // b half (32 rows)
    const int wc   = w & 3;                // n strip (16 cols)
    const int gb8  = (lane >> 4) * 8;      // 16B group (elems)
    const int ram  = wr * 32 + (lane & 15);
    const int rbn  = wc * 16 + (lane & 15);
    const int swzA = (ram & 7) << 3;       // same for ram+16
    const int swzB = (rbn & 7) << 3;
    f32x4 axy0 = {0.f,0.f,0.f,0.f}, axy1 = {0.f,0.f,0.f,0.f};
    f32x4 axa0 = {0.f,0.f,0.f,0.f}, axa1 = {0.f,0.f,0.f,0.f};

    const ushort* r0h = sXh + ram * 256;
    const ushort* r1h = sXh + (ram + 16) * 256;
    const ushort* r0l = sXl + ram * 256;
    const ushort* r1l = sXl + (ram + 16) * 256;
    const ushort* bph = sPh + rbn * 128;
    const ushort* bpl = sPl + rbn * 128;
    const ushort* bah = sAh + rbn * 128;
    const ushort* bal = sAl + rbn * 128;

    // ---- K-half 0: q = 0..3 ----
    #pragma unroll
    for (int q = 0; q < 4; ++q) {
        int kb  = (q * 32 + gb8) ^ swzA;
        int kbB = (q * 32 + gb8) ^ swzB;
        s16x8 xh0 = *(const s16x8*)(r0h + kb);
        s16x8 xh1 = *(const s16x8*)(r1h + kb);
        s16x8 xl0 = *(const s16x8*)(r0l + kb);
        s16x8 xl1 = *(const s16x8*)(r1l + kb);
        s16x8 ph  = *(const s16x8*)(bph + kbB);
        s16x8 pl  = *(const s16x8*)(bpl + kbB);
        s16x8 ah  = *(const s16x8*)(bah + kbB);
        s16x8 al  = *(const s16x8*)(bal + kbB);
        axy0 = MFMA_BF16(xh0, ph, axy0, 0, 0, 0);
        axy0 = MFMA_BF16(xh0, pl, axy0, 0, 0, 0);
        axy0 = MFMA_BF16(xl0, ph, axy0, 0, 0, 0);
        axy1 = MFMA_BF16(xh1, ph, axy1, 0, 0, 0);
        axy1 = MFMA_BF16(xh1, pl, axy1, 0, 0, 0);
        axy1 = MFMA_BF16(xl1, ph, axy1, 0, 0, 0);
        axa0 = MFMA_BF16(xh0, ah, axa0, 0, 0, 0);
        axa0 = MFMA_BF16(xh0, al, axa0, 0, 0, 0);
        axa0 = MFMA_BF16(xl0, ah, axa0, 0, 0, 0);
        axa1 = MFMA_BF16(xh1, ah, axa1, 0, 0, 0);
        axa1 = MFMA_BF16(xh1, al, axa1, 0, 0, 0);
        axa1 = MFMA_BF16(xl1, ah, axa1, 0, 0, 0);
    }

    // ---- swap in K-half 1 of P/A ----
    __syncthreads();                       // all half-0 reads done
    if (lane >= 32) {
        #pragma unroll
        for (int i = 0; i < 8; ++i) {
            int rn = w * 8 + i;
            int cs = c0 ^ ((rn & 7) << 3);
            *(uint2*)&sPh[rn * 128 + cs] = ph1[i];
            *(uint2*)&sPl[rn * 128 + cs] = pl1[i];
            *(uint2*)&sAh[rn * 128 + cs] = ah1[i];
            *(uint2*)&sAl[rn * 128 + cs] = al1[i];
        }
    }
    __syncthreads();                       // half-1 resident

    // ---- K-half 1: q = 4..7 ----
    #pragma unroll
    for (int q = 4; q < 8; ++q) {
        int kb  = (q * 32 + gb8) ^ swzA;           // X: full-K offset
        int kbB = ((q - 4) * 32 + gb8) ^ swzB;     // P/A: half tile reused
        s16x8 xh0 = *(const s16x8*)(r0h + kb);
        s16x8 xh1 = *(const s16x8*)(r1h + kb);
        s16x8 xl0 = *(const s16x8*)(r0l + kb);
        s16x8 xl1 = *(const s16x8*)(r1l + kb);
        s16x8 ph  = *(const s16x8*)(bph + kbB);
        s16x8 pl  = *(const s16x8*)(bpl + kbB);
        s16x8 ah  = *(const s16x8*)(bah + kbB);
        s16x8 al  = *(const s16x8*)(bal + kbB);
        axy0 = MFMA_BF16(xh0, ph, axy0, 0, 0, 0);
        axy0 = MFMA_BF16(xh0, pl, axy0, 0, 0, 0);
        axy0 = MFMA_BF16(xl0, ph, axy0, 0, 0, 0);
        axy1 = MFMA_BF16(xh1, ph, axy1, 0, 0, 0);
        axy1 = MFMA_BF16(xh1, pl, axy1, 0, 0, 0);
        axy1 = MFMA_BF16(xl1, ph, axy1, 0, 0, 0);
        axa0 = MFMA_BF16(xh0, ah, axa0, 0, 0, 0);
        axa0 = MFMA_BF16(xh0, al, axa0, 0, 0, 0);
        axa0 = MFMA_BF16(xl0, ah, axa0, 0, 0, 0);
        axa1 = MFMA_BF16(xh1, ah, axa1, 0, 0, 0);
        axa1 = MFMA_BF16(xh1, al, axa1, 0, 0, 0);
        axa1 = MFMA_BF16(xl1, ah, axa1, 0, 0, 0);
    }

    // ---- epilogue: C/D map col=lane&15, row=(lane>>4)*4+reg ----
    const int n = n0 + rbn;
    const float p2 = p2sl[rbn], pa = pasl[rbn], an = ansl[rbn], kk = ksl[rbn];
    #pragma unroll
    for (int m = 0; m < 2; ++m) {
        f32x4 acc_xy = m ? axy1 : axy0;
        f32x4 acc_xa = m ? axa1 : axa0;
        #pragma unroll
        for (int rg = 0; rg < 4; ++rg) {
            int bl = wr * 32 + m * 16 + (lane >> 4) * 4 + rg;
            float yy  = y2[b0 + bl];
            float xy  = -acc_xy[rg];                     // (-P).X
            float xa  =  acc_xa[rg];
            float dnm = 1.f + 2.f * xy + p2 * yy + 1e-5f;
            float alpha = (1.f + 2.f * xy + yy) / dnm;   // coeff on (-P)
            float beta  = (1.f - p2) / dnm;              // coeff on X
            float num  = 2.f * (beta * xa - alpha * pa);
            float mob2 = alpha * alpha * p2 + beta * beta * yy
                       + 2.f * alpha * beta * xy;
            float den  = an * (1.f - mob2);
            out[(size_t)(b0 + bl) * NN + n] = kk * asinhf(num / den);
        }
    }
}

extern "C" void kernel_launch(void* const* d_in, const int* in_sizes, int n_in,
                              void* d_out, int out_size, void* d_ws, size_t ws_size,
                              hipStream_t stream) {
    const float* x      = (const float*)d_in[0];
    const float* a_vals = (const float*)d_in[1];
    const float* p_vals = (const float*)d_in[2];
    float* out = (float*)d_out;

    ushort* Xh = (ushort*)d_ws;                 // [BB][DD] bf16 hi (pre-swizzled)
    ushort* Xl = Xh + (size_t)BB * DD;
    float*  y2 = (float*)(Xl + (size_t)BB * DD);

    const int dynLds = 131072 + 4 * 64 * 4;     // 132,096 B
    (void)hipFuncSetAttribute(reinterpret_cast<const void*>(hmlr_main),
                              hipFuncAttributeMaxDynamicSharedMemorySize, dynLds);

    hipLaunchKernelGGL(hmlr_xform, dim3(BB / 4), dim3(256), 0, stream,
                       x, Xh, Xl, y2);
    hipLaunchKernelGGL(hmlr_main, dim3(NN / 64, BB / 64), dim3(512), dynLds, stream,
                       a_vals, p_vals, Xh, Xl, y2, out);
}

// Round 11
// 18.289 us; speedup vs baseline: 1.6593x; 1.6593x over previous
//
#include <hip/hip_runtime.h>
#include <math.h>

#define BB 2048   // batch B
#define NN 512    // classes N
#define DD 256    // dim D

typedef __attribute__((ext_vector_type(8))) short s16x8;   // 8 bf16
typedef __attribute__((ext_vector_type(4))) float f32x4;

#define MFMA_BF16 __builtin_amdgcn_mfma_f32_16x16x32_bf16

__device__ __forceinline__ ushort f2bf(float f) {          // RNE f32->bf16
    union { float f; unsigned u; } c; c.f = f;
    return (ushort)((c.u + 0x7fffu + ((c.u >> 16) & 1u)) >> 16);
}
__device__ __forceinline__ float bf2f(ushort h) {
    union { unsigned u; float f; } c; c.u = ((unsigned)h) << 16;
    return c.f;
}

// scale 4 floats, split each into bf16 hi + bf16 lo (RNE both), pack pairs
__device__ __forceinline__ void split4(f32x4 v, float s, uint2* hi, uint2* lo) {
    float a = v.x * s, b = v.y * s, c = v.z * s, d = v.w * s;
    ushort ha = f2bf(a), hb = f2bf(b), hc = f2bf(c), hd = f2bf(d);
    ushort la = f2bf(a - bf2f(ha)), lb = f2bf(b - bf2f(hb));
    ushort lc = f2bf(c - bf2f(hc)), ld = f2bf(d - bf2f(hd));
    hi->x = (unsigned)ha | ((unsigned)hb << 16);
    hi->y = (unsigned)hc | ((unsigned)hd << 16);
    lo->x = (unsigned)la | ((unsigned)lb << 16);
    lo->y = (unsigned)lc | ((unsigned)ld << 16);
}

// stable fast asinh: sign(z) * log(|z| + sqrt(z^2+1))
__device__ __forceinline__ float fast_asinh(float z) {
    float az = fabsf(z);
    float r = __logf(az + sqrtf(fmaf(az, az, 1.0f)));
    return copysignf(r, z);
}

// ---------------- K1: one WAVE per row, no barriers (R5-exact) ----------------
__global__ __launch_bounds__(256) void hmlr_transform(
    const float* __restrict__ x, const float* __restrict__ a_vals,
    const float* __restrict__ p_vals,
    ushort* __restrict__ Xh, ushort* __restrict__ Xl,
    ushort* __restrict__ Ph, ushort* __restrict__ Pl,
    ushort* __restrict__ Ah, ushort* __restrict__ Al,
    float* __restrict__ y2, float* __restrict__ p2s, float* __restrict__ pas,
    float* __restrict__ ans, float* __restrict__ ks)
{
    const int lane = threadIdx.x & 63;
    const int wid  = blockIdx.x * 4 + (threadIdx.x >> 6);   // row id, < BB+NN
    const int e0   = lane * 4;                              // 4 elems per lane

    if (wid < BB) {
        const int r = wid;
        f32x4 v = *(const f32x4*)&x[(size_t)r * DD + e0];
        float ss = v.x * v.x + v.y * v.y + v.z * v.z + v.w * v.w;
        #pragma unroll
        for (int m = 32; m; m >>= 1) ss += __shfl_xor(ss, m, 64);
        float norm0 = sqrtf(ss);
        float fac = fminf(1.0f, 1.0f / (norm0 + 1e-5f));    // CLIP_R = 1
        float u = fmaxf(norm0 * fac, 1e-5f);
        float th = tanhf(u);                                 // sqrt_c = 1
        float en = fmaxf(th, 1e-5f);
        float wgt = (en > 0.999f) ? (0.999f / en) : 1.0f;    // project
        float s = fac * (th / u) * wgt;                      // x -> xb scale
        if (lane == 0) { float fn = th * wgt; y2[r] = fn * fn; }
        uint2 hi, lo;
        split4(v, s, &hi, &lo);
        int es = e0 ^ ((r & 7) << 3);                        // pre-swizzle
        *(uint2*)&Xh[(size_t)r * DD + es] = hi;
        *(uint2*)&Xl[(size_t)r * DD + es] = lo;
    } else {
        const int n = wid - BB;
        f32x4 pv = *(const f32x4*)&p_vals[(size_t)n * DD + e0];
        f32x4 av = *(const f32x4*)&a_vals[(size_t)n * DD + e0];
        float sp = pv.x * pv.x + pv.y * pv.y + pv.z * pv.z + pv.w * pv.w;
        float sa = av.x * av.x + av.y * av.y + av.z * av.z + av.w * av.w;
        float sx = pv.x * av.x + pv.y * av.y + pv.z * av.z + pv.w * av.w;
        #pragma unroll
        for (int m = 32; m; m >>= 1) {
            sp += __shfl_xor(sp, m, 64);
            sa += __shfl_xor(sa, m, 64);
            sx += __shfl_xor(sx, m, 64);
        }
        float u = fmaxf(sqrtf(sp), 1e-5f);
        float th = tanhf(u);
        float spp = th / u;                                  // p -> p_poincare
        float p2 = th * th;
        float conf = 1.0f - p2;                              // conformal
        if (lane == 0) {
            p2s[n] = p2;
            pas[n] = spp * conf * sx;                        // P . A
            float an = sqrtf(sa) * conf;                     // ||a_poincare||
            ans[n] = an;
            ks[n] = (2.0f / conf) * an;                      // lam * a_norm
        }
        int es = e0 ^ ((n & 7) << 3);
        uint2 hi, lo;
        split4(pv, spp, &hi, &lo);
        *(uint2*)&Ph[(size_t)n * DD + es] = hi;
        *(uint2*)&Pl[(size_t)n * DD + es] = lo;
        split4(av, conf, &hi, &lo);
        *(uint2*)&Ah[(size_t)n * DD + es] = hi;
        *(uint2*)&Al[(size_t)n * DD + es] = lo;
    }
}

// ---------------- K2: 64x64 tile, 8 waves, BK=64 dbuf (R5-exact core) --------
// Deltas vs R5: XCD-aware bid->(b0,n0) mapping; early pinned scalar prefetch;
// inline fast asinh.
__global__ __launch_bounds__(512) void hmlr_gemm(
    const ushort* __restrict__ Xh, const ushort* __restrict__ Xl,
    const ushort* __restrict__ Ph, const ushort* __restrict__ Pl,
    const ushort* __restrict__ Ah, const ushort* __restrict__ Al,
    const float* __restrict__ y2, const float* __restrict__ p2s,
    const float* __restrict__ pas, const float* __restrict__ ans,
    const float* __restrict__ ks, float* __restrict__ out)
{
    extern __shared__ ushort T[];          // [2][6][64][64]

    const int t    = threadIdx.x;
    const int lane = t & 63;
    const int w    = t >> 6;               // wave 0..7
    const int bid  = blockIdx.x;
    // XCD-aware mapping: xcd = bid&7 (dispatch round-robin). All 8 blocks
    // sharing one b0 (same X rows) land on the SAME xcd -> X re-reads L2-hit.
    const int xcd  = bid & 7;
    const int j    = bid >> 3;             // 0..31
    const int b0   = (xcd * 4 + (j >> 3)) * 64;
    const int n0   = (j & 7) * 64;
    const int wr   = w >> 2;               // m half: 32 rows
    const int wc   = w & 3;                // n strip: 16 cols

    const ushort* bases[6] = {Xh, Xl, Ph, Pl, Ah, Al};

    f32x4 axy0 = {0.f,0.f,0.f,0.f}, axy1 = {0.f,0.f,0.f,0.f};
    f32x4 axa0 = {0.f,0.f,0.f,0.f}, axa1 = {0.f,0.f,0.f,0.f};

    // Stage one BK=64 slice of all 6 mats (48 KiB) into buf. 48 wave-chunks:
    auto stage = [&](int buf, int s) {
        #pragma unroll
        for (int i = 0; i < 6; ++i) {
            int g = w * 6 + i;
            int mat = g >> 3;
            int sub = g & 7;
            int grow = (mat < 2 ? b0 : n0) + sub * 8 + (lane >> 3);
            const ushort* src = bases[mat] + (size_t)grow * DD + s * 64 + (lane & 7) * 8;
            const ushort* dst = T + (((buf * 6 + mat) * 64 + sub * 8) * 64);
            __builtin_amdgcn_global_load_lds(
                (const __attribute__((address_space(1))) unsigned int*)(const void*)src,
                (__attribute__((address_space(3))) unsigned int*)(void*)dst,
                16, 0, 0);
        }
    };

    const int ram = wr * 32 + (lane & 15);
    const int rbn = wc * 16 + (lane & 15);
    const int gb  = (lane >> 4) << 4;      // 16B group within 64B half-row

    stage(0, 0);

    // ---- early epilogue-scalar prefetch (overlaps staging/MFMA) ----
    const int n = n0 + rbn;
    float p2 = p2s[n], pa = pas[n], an = ans[n], kk = ks[n];
    float yv[8];
    #pragma unroll
    for (int m = 0; m < 2; ++m)
        #pragma unroll
        for (int rg = 0; rg < 4; ++rg)
            yv[m * 4 + rg] = y2[b0 + wr * 32 + m * 16 + (lane >> 4) * 4 + rg];
    asm volatile("" :: "v"(p2), "v"(pa), "v"(an), "v"(kk));
    #pragma unroll
    for (int i = 0; i < 8; ++i) asm volatile("" :: "v"(yv[i]));

    for (int s = 0; s < 4; ++s) {
        __syncthreads();                   // vmcnt drain: buf[s&1] ready
        if (s < 3) stage((s + 1) & 1, s + 1);
        const int bf = s & 1;
        #pragma unroll
        for (int ksl = 0; ksl < 2; ++ksl) {
            const int kb = ksl * 64 + gb;
            const ushort* base = T + (bf * 6 * 64 * 64);
            const char* x0 = (const char*)(base + (0 * 64 + ram) * 64);
            const char* x1 = (const char*)(base + (1 * 64 + ram) * 64);
            const int sa0 = kb ^ ((ram & 7) << 4);
            const int sb0 = kb ^ ((rbn & 7) << 4);
            const int sa1 = kb ^ (((ram + 16) & 7) << 4);   // == sa0
            s16x8 xh0 = *(const s16x8*)(x0 + sa0);
            s16x8 xh1 = *(const s16x8*)(x0 + 16 * 128 + sa1);
            s16x8 xl0 = *(const s16x8*)(x1 + sa0);
            s16x8 xl1 = *(const s16x8*)(x1 + 16 * 128 + sa1);
            s16x8 ph  = *(const s16x8*)((const char*)(base + (2 * 64 + rbn) * 64) + sb0);
            s16x8 pl  = *(const s16x8*)((const char*)(base + (3 * 64 + rbn) * 64) + sb0);
            s16x8 ah  = *(const s16x8*)((const char*)(base + (4 * 64 + rbn) * 64) + sb0);
            s16x8 al  = *(const s16x8*)((const char*)(base + (5 * 64 + rbn) * 64) + sb0);
            axy0 = MFMA_BF16(xh0, ph, axy0, 0, 0, 0);
            axy0 = MFMA_BF16(xh0, pl, axy0, 0, 0, 0);
            axy0 = MFMA_BF16(xl0, ph, axy0, 0, 0, 0);
            axy1 = MFMA_BF16(xh1, ph, axy1, 0, 0, 0);
            axy1 = MFMA_BF16(xh1, pl, axy1, 0, 0, 0);
            axy1 = MFMA_BF16(xl1, ph, axy1, 0, 0, 0);
            axa0 = MFMA_BF16(xh0, ah, axa0, 0, 0, 0);
            axa0 = MFMA_BF16(xh0, al, axa0, 0, 0, 0);
            axa0 = MFMA_BF16(xl0, ah, axa0, 0, 0, 0);
            axa1 = MFMA_BF16(xh1, ah, axa1, 0, 0, 0);
            axa1 = MFMA_BF16(xh1, al, axa1, 0, 0, 0);
            axa1 = MFMA_BF16(xl1, ah, axa1, 0, 0, 0);
        }
    }

    // Epilogue. C/D map: col = lane&15, row = (lane>>4)*4 + reg.
    #pragma unroll
    for (int m = 0; m < 2; ++m) {
        f32x4 acc_xy = m ? axy1 : axy0;
        f32x4 acc_xa = m ? axa1 : axa0;
        #pragma unroll
        for (int rg = 0; rg < 4; ++rg) {
            int b = b0 + wr * 32 + m * 16 + (lane >> 4) * 4 + rg;
            float yy  = yv[m * 4 + rg];
            float xy  = -acc_xy[rg];                     // (-P).X
            float xa  =  acc_xa[rg];
            float dnm = 1.f + 2.f * xy + p2 * yy + 1e-5f;
            float alpha = (1.f + 2.f * xy + yy) / dnm;   // coeff on (-P)
            float beta  = (1.f - p2) / dnm;              // coeff on X
            float num  = 2.f * (beta * xa - alpha * pa);
            float mob2 = alpha * alpha * p2 + beta * beta * yy
                       + 2.f * alpha * beta * xy;
            float den  = an * (1.f - mob2);
            out[(size_t)b * NN + n] = kk * fast_asinh(num / den);
        }
    }
}

extern "C" void kernel_launch(void* const* d_in, const int* in_sizes, int n_in,
                              void* d_out, int out_size, void* d_ws, size_t ws_size,
                              hipStream_t stream) {
    const float* x      = (const float*)d_in[0];
    const float* a_vals = (const float*)d_in[1];
    const float* p_vals = (const float*)d_in[2];
    float* out = (float*)d_out;

    ushort* Xh = (ushort*)d_ws;                 // [BB][DD] bf16 hi (pre-swizzled)
    ushort* Xl = Xh + (size_t)BB * DD;
    ushort* Ph = Xl + (size_t)BB * DD;          // [NN][DD]
    ushort* Pl = Ph + (size_t)NN * DD;
    ushort* Ah = Pl + (size_t)NN * DD;
    ushort* Al = Ah + (size_t)NN * DD;
    float*  y2  = (float*)(Al + (size_t)NN * DD);
    float*  p2s = y2 + BB;
    float*  pas = p2s + NN;
    float*  ans = pas + NN;
    float*  ks  = ans + NN;

    (void)hipFuncSetAttribute(reinterpret_cast<const void*>(hmlr_gemm),
                              hipFuncAttributeMaxDynamicSharedMemorySize, 98304);

    hipLaunchKernelGGL(hmlr_transform, dim3((BB + NN) / 4), dim3(256), 0, stream,
                       x, a_vals, p_vals, Xh, Xl, Ph, Pl, Ah, Al,
                       y2, p2s, pas, ans, ks);
    hipLaunchKernelGGL(hmlr_gemm, dim3(256), dim3(512), 98304, stream,
                       Xh, Xl, Ph, Pl, Ah, Al, y2, p2s, pas, ans, ks, out);
}